// Round 2
// baseline (981.544 us; speedup 1.0000x reference)
//
#include <hip/hip_runtime.h>
#include <cstdint>
#include <cstddef>

typedef __attribute__((ext_vector_type(8))) short s16x8;
typedef __attribute__((ext_vector_type(8))) _Float16 f16x8;
typedef __attribute__((ext_vector_type(4))) float f32x4;

__device__ __forceinline__ unsigned short f2h(float f) {
  union { _Float16 h; unsigned short u; } x;
  x.h = (_Float16)f;  // v_cvt_f16_f32, RTNE
  return x.u;
}

__device__ __forceinline__ f16x8 ldh8(const unsigned short* p) {
  union { s16x8 s; f16x8 h; } u;
  u.s = *(const s16x8*)p;
  return u.h;
}

#define GLD_LDS16(g, l)                                                        \
  __builtin_amdgcn_global_load_lds(                                            \
      (const __attribute__((address_space(1))) void*)(g),                      \
      (__attribute__((address_space(3))) void*)(l), 16, 0, 0)

// ---------------------------------------------------------------- LayerNorm
__global__ __launch_bounds__(256) void ln_kernel(
    const float* __restrict__ x, const float* __restrict__ gw,
    const float* __restrict__ gb, unsigned short* __restrict__ y) {
  const int row = blockIdx.x;
  const int t = threadIdx.x;
  const int w = t >> 6, l = t & 63;
  const float* xr = x + (size_t)row * 2048 + t * 8;
  float4 a = *(const float4*)xr;
  float4 c = *(const float4*)(xr + 4);
  float s = a.x + a.y + a.z + a.w + c.x + c.y + c.z + c.w;
  float q = a.x * a.x + a.y * a.y + a.z * a.z + a.w * a.w +
            c.x * c.x + c.y * c.y + c.z * c.z + c.w * c.w;
#pragma unroll
  for (int off = 1; off < 64; off <<= 1) {
    s += __shfl_xor(s, off);
    q += __shfl_xor(q, off);
  }
  __shared__ float red[8];
  if (l == 0) { red[w] = s; red[4 + w] = q; }
  __syncthreads();
  s = red[0] + red[1] + red[2] + red[3];
  q = red[4] + red[5] + red[6] + red[7];
  const float mu = s * (1.0f / 2048.0f);
  const float var = q * (1.0f / 2048.0f) - mu * mu;
  const float rs = rsqrtf(var + 1e-8f);
  float4 w0 = *(const float4*)(gw + t * 8);
  float4 w1 = *(const float4*)(gw + t * 8 + 4);
  float4 b0 = *(const float4*)(gb + t * 8);
  float4 b1 = *(const float4*)(gb + t * 8 + 4);
  s16x8 ov;
  ov[0] = (short)f2h((a.x - mu) * rs * w0.x + b0.x);
  ov[1] = (short)f2h((a.y - mu) * rs * w0.y + b0.y);
  ov[2] = (short)f2h((a.z - mu) * rs * w0.z + b0.z);
  ov[3] = (short)f2h((a.w - mu) * rs * w0.w + b0.w);
  ov[4] = (short)f2h((c.x - mu) * rs * w1.x + b1.x);
  ov[5] = (short)f2h((c.y - mu) * rs * w1.y + b1.y);
  ov[6] = (short)f2h((c.z - mu) * rs * w1.z + b1.z);
  ov[7] = (short)f2h((c.w - mu) * rs * w1.w + b1.w);
  *(s16x8*)(y + (size_t)row * 2048 + t * 8) = ov;
}

// -------------------------------------- weight transpose f32[R][C] -> f16[C][R]
__global__ __launch_bounds__(256) void transpose_w_kernel(
    const float* __restrict__ in, unsigned short* __restrict__ out,
    int R, int C) {
  __shared__ float tile[32][33];
  const int c0 = blockIdx.x * 32, r0 = blockIdx.y * 32;
  const int x = threadIdx.x, y = threadIdx.y;
#pragma unroll
  for (int k = 0; k < 4; ++k)
    tile[y + k * 8][x] = in[(size_t)(r0 + y + k * 8) * C + c0 + x];
  __syncthreads();
#pragma unroll
  for (int k = 0; k < 4; ++k)
    out[(size_t)(c0 + y + k * 8) * R + r0 + x] = f2h(tile[x][y + k * 8]);
}

// -------------------------------------- V transpose f16 [bh][1024][256] -> [bh][256][1024]
__global__ __launch_bounds__(256) void transpose_v_kernel(
    const unsigned short* __restrict__ in, unsigned short* __restrict__ out) {
  __shared__ unsigned short tile[32][33];
  const int bh = blockIdx.z;
  const int d0 = blockIdx.x * 32, t0 = blockIdx.y * 32;
  const unsigned short* ip = in + (size_t)bh * 1024 * 256;
  unsigned short* op = out + (size_t)bh * 256 * 1024;
  const int x = threadIdx.x, y = threadIdx.y;
#pragma unroll
  for (int k = 0; k < 4; ++k)
    tile[y + k * 8][x] = ip[(size_t)(t0 + y + k * 8) * 256 + d0 + x];
  __syncthreads();
#pragma unroll
  for (int k = 0; k < 4; ++k)
    op[(size_t)(d0 + y + k * 8) * 1024 + t0 + x] = tile[x][y + k * 8];
}

// ---------------------------------------------------------------- GEMM (A row-major, Bt = B^T row-major, K-contig both)
__device__ __forceinline__ void stage128x32(const unsigned short* gbase, int ldg,
                                            unsigned short* lds, int w, int l) {
  // Stages a 128x32 f16 tile. LDS is linear; source k-slot is pre-swizzled so
  // that LDS[row][phys_slot] = G[row][phys_slot ^ ((row>>1)&3)] (16B slots).
#pragma unroll
  for (int i = 0; i < 2; ++i) {
    const int r = (i * 4 + w) * 16 + (l >> 2);
    const int slot = (l & 3) ^ ((l >> 3) & 3);
    const unsigned short* src = gbase + (size_t)r * ldg + slot * 8;
    GLD_LDS16(src, lds + (i * 4 + w) * 512);
  }
}

template <int MODE>
__global__ __launch_bounds__(256, 2) void gemm_bt_kernel(
    const unsigned short* __restrict__ A, const unsigned short* __restrict__ Bt,
    const int K,
    unsigned short* __restrict__ qb, unsigned short* __restrict__ kb,
    unsigned short* __restrict__ vb,
    const float* __restrict__ resid, float* __restrict__ outp) {
  __shared__ __align__(16) unsigned short lds_a[128 * 32];
  __shared__ __align__(16) unsigned short lds_b[128 * 32];
  const int tid = threadIdx.x;
  const int w = tid >> 6, l = tid & 63;
  const int m0 = blockIdx.y * 128, n0 = blockIdx.x * 128;
  const int wm = (w >> 1) * 64, wn = (w & 1) * 64;
  const int lr = l & 15, lg = l >> 4;
  const f32x4 zero = {0.f, 0.f, 0.f, 0.f};
  f32x4 acc[4][4];
#pragma unroll
  for (int m = 0; m < 4; ++m)
#pragma unroll
    for (int n = 0; n < 4; ++n) acc[m][n] = zero;
  const unsigned short* Abase = A + (size_t)m0 * K;
  const unsigned short* Bbase = Bt + (size_t)n0 * K;

  for (int k0 = 0; k0 < K; k0 += 32) {
    __syncthreads();
    stage128x32(Abase + k0, K, lds_a, w, l);
    stage128x32(Bbase + k0, K, lds_b, w, l);
    __syncthreads();
    f16x8 af[4], bfr[4];
#pragma unroll
    for (int m = 0; m < 4; ++m) {
      const int row = wm + m * 16 + lr;
      af[m] = ldh8(&lds_a[row * 32 + ((lg ^ ((row >> 1) & 3)) << 3)]);
    }
#pragma unroll
    for (int n = 0; n < 4; ++n) {
      const int row = wn + n * 16 + lr;
      bfr[n] = ldh8(&lds_b[row * 32 + ((lg ^ ((row >> 1) & 3)) << 3)]);
    }
#pragma unroll
    for (int m = 0; m < 4; ++m)
#pragma unroll
      for (int n = 0; n < 4; ++n)
        acc[m][n] = __builtin_amdgcn_mfma_f32_16x16x32_f16(af[m], bfr[n],
                                                           acc[m][n], 0, 0, 0);
  }

#pragma unroll
  for (int m = 0; m < 4; ++m) {
#pragma unroll
    for (int n = 0; n < 4; ++n) {
      const int gn = n0 + wn + n * 16 + lr;
#pragma unroll
      for (int reg = 0; reg < 4; ++reg) {
        const int gm = m0 + wm + m * 16 + lg * 4 + reg;
        const float v = acc[m][n][reg];
        if constexpr (MODE == 0) {
          const int which = gn >> 11;
          const int head = (gn >> 8) & 7;
          const int d = gn & 255;
          const int b = gm >> 10, t = gm & 1023;
          unsigned short* dst = (which == 0) ? qb : (which == 1) ? kb : vb;
          dst[(((size_t)b * 8 + head) * 1024 + t) * 256 + d] = f2h(v);
        } else {
          outp[(size_t)gm * 2048 + gn] = v + resid[(size_t)gm * 2048 + gn];
        }
      }
    }
  }
}

// ---------------------------------------------------------------- flash attention
__global__ __launch_bounds__(256, 2) void attn_kernel(
    const unsigned short* __restrict__ qbuf, const unsigned short* __restrict__ kbuf,
    const unsigned short* __restrict__ vT, const int* __restrict__ mask,
    const int* __restrict__ pre, unsigned short* __restrict__ ctx) {
  __shared__ __align__(16) unsigned short plds[4 * 16 * 64];
  const int tid = threadIdx.x;
  const int w = tid >> 6, l = tid & 63;
  const int lr = l & 15, lg = l >> 4;
  const int qb0 = blockIdx.x * 64;
  const int bh = blockIdx.y;
  const int b = bh >> 3, h = bh & 7;
  const int isPre = pre[0];
  const int qrow0 = qb0 + w * 16;
  const unsigned short* qrow =
      qbuf + ((size_t)bh * 1024 + qrow0 + lr) * 256 + lg * 8;
  f16x8 qf[8];
#pragma unroll
  for (int kk = 0; kk < 8; ++kk) qf[kk] = ldh8(qrow + kk * 32);
  const f32x4 zero = {0.f, 0.f, 0.f, 0.f};
  f32x4 oacc[16];
#pragma unroll
  for (int dt = 0; dt < 16; ++dt) oacc[dt] = zero;
  float mrow[4] = {-1e30f, -1e30f, -1e30f, -1e30f};
  float lrow[4] = {0.f, 0.f, 0.f, 0.f};
  const int* mk = mask + b * 1024;
  unsigned short* pl = plds + w * 1024;
  const unsigned short* kbh = kbuf + (size_t)bh * 1024 * 256;
  const unsigned short* vbh = vT + (size_t)bh * 256 * 1024;

  for (int kv0 = 0; kv0 < 1024; kv0 += 64) {
    f32x4 sacc[4];
#pragma unroll
    for (int n = 0; n < 4; ++n) sacc[n] = zero;
#pragma unroll
    for (int kk = 0; kk < 8; ++kk) {
#pragma unroll
      for (int n = 0; n < 4; ++n) {
        const f16x8 kf = ldh8(kbh + (size_t)(kv0 + n * 16 + lr) * 256 +
                              kk * 32 + lg * 8);
        sacc[n] = __builtin_amdgcn_mfma_f32_16x16x32_f16(qf[kk], kf, sacc[n], 0, 0, 0);
      }
    }
    int mv[4];
#pragma unroll
    for (int n = 0; n < 4; ++n) mv[n] = mk[kv0 + n * 16 + lr];
    float p[4][4];
    float sf[4];
#pragma unroll
    for (int reg = 0; reg < 4; ++reg) {
      const int qg = qrow0 + lg * 4 + reg;
      float mx = -3.0e38f;
#pragma unroll
      for (int n = 0; n < 4; ++n) {
        const int kvg = kv0 + n * 16 + lr;
        float s = sacc[n][reg];
        const bool msk = (mv[n] != 0) || (isPre && (kvg > qg));
        s = msk ? -1e9f : s;
        s *= 0.0625f;  // masked_fill THEN scale, matching reference
        p[n][reg] = s;
        mx = fmaxf(mx, s);
      }
      mx = fmaxf(mx, __shfl_xor(mx, 1));
      mx = fmaxf(mx, __shfl_xor(mx, 2));
      mx = fmaxf(mx, __shfl_xor(mx, 4));
      mx = fmaxf(mx, __shfl_xor(mx, 8));
      const float mnew = fmaxf(mrow[reg], mx);
      sf[reg] = __expf(mrow[reg] - mnew);
      float ps = 0.f;
#pragma unroll
      for (int n = 0; n < 4; ++n) {
        const float pv = __expf(p[n][reg] - mnew);
        p[n][reg] = pv;
        ps += pv;
      }
      ps += __shfl_xor(ps, 1);
      ps += __shfl_xor(ps, 2);
      ps += __shfl_xor(ps, 4);
      ps += __shfl_xor(ps, 8);
      lrow[reg] = lrow[reg] * sf[reg] + ps;
      mrow[reg] = mnew;
    }
#pragma unroll
    for (int dt = 0; dt < 16; ++dt) {
      f32x4 o = oacc[dt];
      o[0] *= sf[0]; o[1] *= sf[1]; o[2] *= sf[2]; o[3] *= sf[3];
      oacc[dt] = o;
    }
    // P -> per-wave LDS region, XOR-swizzled (8 slots/row of 16B)
#pragma unroll
    for (int n = 0; n < 4; ++n) {
#pragma unroll
      for (int reg = 0; reg < 4; ++reg) {
        const int row = lg * 4 + reg;
        const int col = n * 16 + lr;
        const int slot = col >> 3;
        pl[row * 64 + (((slot ^ ((row >> 1) & 7)) << 3) | (col & 7))] =
            f2h(p[n][reg]);
      }
    }
    asm volatile("s_waitcnt lgkmcnt(0)" ::: "memory");
#pragma unroll
    for (int kb2 = 0; kb2 < 2; ++kb2) {
      const int row = lr;
      const f16x8 pf = ldh8(
          &pl[row * 64 + (((kb2 * 4 + lg) ^ ((row >> 1) & 7)) << 3)]);
#pragma unroll
      for (int dt = 0; dt < 16; ++dt) {
        const f16x8 vf = ldh8(vbh + (size_t)(dt * 16 + lr) * 1024 +
                              kv0 + kb2 * 32 + lg * 8);
        oacc[dt] = __builtin_amdgcn_mfma_f32_16x16x32_f16(pf, vf, oacc[dt], 0, 0, 0);
      }
    }
  }
  float inv[4];
#pragma unroll
  for (int reg = 0; reg < 4; ++reg) inv[reg] = 1.0f / lrow[reg];
#pragma unroll
  for (int dt = 0; dt < 16; ++dt) {
#pragma unroll
    for (int reg = 0; reg < 4; ++reg) {
      const int qg = qrow0 + lg * 4 + reg;
      ctx[((size_t)b * 1024 + qg) * 2048 + h * 256 + dt * 16 + lr] =
          f2h(oacc[dt][reg] * inv[reg]);
    }
  }
}

// ---------------------------------------------------------------- launch
extern "C" void kernel_launch(void* const* d_in, const int* in_sizes, int n_in,
                              void* d_out, int out_size, void* d_ws,
                              size_t ws_size, hipStream_t stream) {
  const float* x_in = (const float*)d_in[0];
  const int* mask = (const int*)d_in[1];
  const float* lnw = (const float*)d_in[2];
  const float* lnb = (const float*)d_in[3];
  const float* qkvw = (const float*)d_in[4];
  const float* ow = (const float*)d_in[5];
  const int* ispre = (const int*)d_in[6];
  float* out = (float*)d_out;
  char* ws = (char*)d_ws;

  const size_t SZ = 33554432;  // 8192*2048*2 bytes
  unsigned short* xln = (unsigned short*)(ws);           // dead after gemm_qkv
  unsigned short* wTq = (unsigned short*)(ws + SZ);      // 25165824
  unsigned short* oT = (unsigned short*)(ws + SZ + 25165824);  // 8388608
  unsigned short* qb;
  unsigned short* kb;
  unsigned short* vb;
  const size_t base = SZ + 25165824 + 8388608;  // 67108864
  if (ws_size >= base + 3 * SZ) {
    qb = (unsigned short*)(ws + base);
    kb = (unsigned short*)(ws + base + SZ);
    vb = (unsigned short*)(ws + base + 2 * SZ);
  } else {
    // fallback: park q/k in d_out (dead before the final GEMM writes it)
    qb = (unsigned short*)d_out;
    kb = qb + SZ / 2;
    vb = (unsigned short*)(ws + base);
  }
  unsigned short* vT = xln;  // alias: xln dead once gemm_qkv is done
  unsigned short* ctxb = vb; // alias: vb dead once transpose_v is done

  ln_kernel<<<8192, 256, 0, stream>>>(x_in, lnw, lnb, xln);
  transpose_w_kernel<<<dim3(192, 64), dim3(32, 8), 0, stream>>>(qkvw, wTq, 2048, 6144);
  transpose_w_kernel<<<dim3(64, 64), dim3(32, 8), 0, stream>>>(ow, oT, 2048, 2048);
  gemm_bt_kernel<0><<<dim3(48, 64), 256, 0, stream>>>(
      xln, wTq, 2048, qb, kb, vb, nullptr, nullptr);
  transpose_v_kernel<<<dim3(8, 32, 64), dim3(32, 8), 0, stream>>>(vb, vT);
  attn_kernel<<<dim3(16, 64), 256, 0, stream>>>(qb, kb, vT, mask, ispre, ctxb);
  gemm_bt_kernel<1><<<dim3(16, 64), 256, 0, stream>>>(
      ctxb, oT, 2048, nullptr, nullptr, nullptr, x_in, out);
}

// Round 4
// 725.458 us; speedup vs baseline: 1.3530x; 1.3530x over previous
//
#include <hip/hip_runtime.h>
#include <cstdint>
#include <cstddef>

typedef __attribute__((ext_vector_type(8))) short s16x8;
typedef __attribute__((ext_vector_type(8))) _Float16 f16x8;
typedef __attribute__((ext_vector_type(4))) float f32x4;

__device__ __forceinline__ unsigned short f2h(float f) {
  union { _Float16 h; unsigned short u; } x;
  x.h = (_Float16)f;  // v_cvt_f16_f32, RTNE
  return x.u;
}

__device__ __forceinline__ f16x8 ldh8(const unsigned short* p) {
  union { s16x8 s; f16x8 h; } u;
  u.s = *(const s16x8*)p;
  return u.h;
}

#define GLD_LDS16(g, l)                                                        \
  __builtin_amdgcn_global_load_lds(                                            \
      (const __attribute__((address_space(1))) void*)(g),                      \
      (__attribute__((address_space(3))) void*)(l), 16, 0, 0)

// ---------------------------------------------------------------- LayerNorm
__global__ __launch_bounds__(256) void ln_kernel(
    const float* __restrict__ x, const float* __restrict__ gw,
    const float* __restrict__ gb, unsigned short* __restrict__ y) {
  const int row = blockIdx.x;
  const int t = threadIdx.x;
  const int w = t >> 6, l = t & 63;
  const float* xr = x + (size_t)row * 2048 + t * 8;
  float4 a = *(const float4*)xr;
  float4 c = *(const float4*)(xr + 4);
  float s = a.x + a.y + a.z + a.w + c.x + c.y + c.z + c.w;
  float q = a.x * a.x + a.y * a.y + a.z * a.z + a.w * a.w +
            c.x * c.x + c.y * c.y + c.z * c.z + c.w * c.w;
#pragma unroll
  for (int off = 1; off < 64; off <<= 1) {
    s += __shfl_xor(s, off);
    q += __shfl_xor(q, off);
  }
  __shared__ float red[8];
  if (l == 0) { red[w] = s; red[4 + w] = q; }
  __syncthreads();
  s = red[0] + red[1] + red[2] + red[3];
  q = red[4] + red[5] + red[6] + red[7];
  const float mu = s * (1.0f / 2048.0f);
  const float var = q * (1.0f / 2048.0f) - mu * mu;
  const float rs = rsqrtf(var + 1e-8f);
  float4 w0 = *(const float4*)(gw + t * 8);
  float4 w1 = *(const float4*)(gw + t * 8 + 4);
  float4 b0 = *(const float4*)(gb + t * 8);
  float4 b1 = *(const float4*)(gb + t * 8 + 4);
  s16x8 ov;
  ov[0] = (short)f2h((a.x - mu) * rs * w0.x + b0.x);
  ov[1] = (short)f2h((a.y - mu) * rs * w0.y + b0.y);
  ov[2] = (short)f2h((a.z - mu) * rs * w0.z + b0.z);
  ov[3] = (short)f2h((a.w - mu) * rs * w0.w + b0.w);
  ov[4] = (short)f2h((c.x - mu) * rs * w1.x + b1.x);
  ov[5] = (short)f2h((c.y - mu) * rs * w1.y + b1.y);
  ov[6] = (short)f2h((c.z - mu) * rs * w1.z + b1.z);
  ov[7] = (short)f2h((c.w - mu) * rs * w1.w + b1.w);
  *(s16x8*)(y + (size_t)row * 2048 + t * 8) = ov;
}

// -------------------------------------- weight transpose f32[R][C] -> f16[C][R]
__global__ __launch_bounds__(256) void transpose_w_kernel(
    const float* __restrict__ in, unsigned short* __restrict__ out,
    int R, int C) {
  __shared__ float tile[32][33];
  const int c0 = blockIdx.x * 32, r0 = blockIdx.y * 32;
  const int x = threadIdx.x, y = threadIdx.y;
#pragma unroll
  for (int k = 0; k < 4; ++k)
    tile[y + k * 8][x] = in[(size_t)(r0 + y + k * 8) * C + c0 + x];
  __syncthreads();
#pragma unroll
  for (int k = 0; k < 4; ++k)
    out[(size_t)(c0 + y + k * 8) * R + r0 + x] = f2h(tile[x][y + k * 8]);
}

// -------------------------------------- V transpose f16 [bh][1024][256] -> [bh][256][1024]
__global__ __launch_bounds__(256) void transpose_v_kernel(
    const unsigned short* __restrict__ in, unsigned short* __restrict__ out) {
  __shared__ unsigned short tile[32][33];
  const int bh = blockIdx.z;
  const int d0 = blockIdx.x * 32, t0 = blockIdx.y * 32;
  const unsigned short* ip = in + (size_t)bh * 1024 * 256;
  unsigned short* op = out + (size_t)bh * 256 * 1024;
  const int x = threadIdx.x, y = threadIdx.y;
#pragma unroll
  for (int k = 0; k < 4; ++k)
    tile[y + k * 8][x] = ip[(size_t)(t0 + y + k * 8) * 256 + d0 + x];
  __syncthreads();
#pragma unroll
  for (int k = 0; k < 4; ++k)
    op[(size_t)(d0 + y + k * 8) * 1024 + t0 + x] = tile[x][y + k * 8];
}

// ---------------------------------------------------------------- GEMM (A row-major, Bt = B^T row-major, K-contig both)
__device__ __forceinline__ void stage128x32(const unsigned short* gbase, int ldg,
                                            unsigned short* lds, int w, int l) {
  // Stages a 128x32 f16 tile. LDS is linear; source k-slot is pre-swizzled so
  // that LDS[row][phys_slot] = G[row][phys_slot ^ ((row>>1)&3)] (16B slots).
#pragma unroll
  for (int i = 0; i < 2; ++i) {
    const int r = (i * 4 + w) * 16 + (l >> 2);
    const int slot = (l & 3) ^ ((l >> 3) & 3);
    const unsigned short* src = gbase + (size_t)r * ldg + slot * 8;
    GLD_LDS16(src, lds + (i * 4 + w) * 512);
  }
}

template <int MODE>
__global__ __launch_bounds__(256, 2) void gemm_bt_kernel(
    const unsigned short* __restrict__ A, const unsigned short* __restrict__ Bt,
    const int K, const int NB,
    unsigned short* __restrict__ qb, unsigned short* __restrict__ kb,
    unsigned short* __restrict__ vb,
    const float* __restrict__ resid, float* __restrict__ outp) {
  __shared__ __align__(16) unsigned short lds_a[128 * 32];
  __shared__ __align__(16) unsigned short lds_b[128 * 32];
  const int tid = threadIdx.x;
  const int w = tid >> 6, l = tid & 63;
  // XCD-chunk swizzle (bijective: gridDim.x % 8 == 0): co-locate consecutive
  // logical blocks (same m-panel) on one XCD for L2 reuse of the A panel.
  const int flat = blockIdx.x;
  const int cpx = gridDim.x >> 3;
  const int swz = (flat & 7) * cpx + (flat >> 3);
  const int m0 = (swz / NB) * 128, n0 = (swz % NB) * 128;
  const int wm = (w >> 1) * 64, wn = (w & 1) * 64;
  const int lr = l & 15, lg = l >> 4;
  const f32x4 zero = {0.f, 0.f, 0.f, 0.f};
  f32x4 acc[4][4];
#pragma unroll
  for (int m = 0; m < 4; ++m)
#pragma unroll
    for (int n = 0; n < 4; ++n) acc[m][n] = zero;
  const unsigned short* Abase = A + (size_t)m0 * K;
  const unsigned short* Bbase = Bt + (size_t)n0 * K;

  for (int k0 = 0; k0 < K; k0 += 32) {
    __syncthreads();
    stage128x32(Abase + k0, K, lds_a, w, l);
    stage128x32(Bbase + k0, K, lds_b, w, l);
    __syncthreads();
    f16x8 af[4], bfr[4];
#pragma unroll
    for (int m = 0; m < 4; ++m) {
      const int row = wm + m * 16 + lr;
      af[m] = ldh8(&lds_a[row * 32 + ((lg ^ ((row >> 1) & 3)) << 3)]);
    }
#pragma unroll
    for (int n = 0; n < 4; ++n) {
      const int row = wn + n * 16 + lr;
      bfr[n] = ldh8(&lds_b[row * 32 + ((lg ^ ((row >> 1) & 3)) << 3)]);
    }
    __builtin_amdgcn_s_setprio(1);
#pragma unroll
    for (int m = 0; m < 4; ++m)
#pragma unroll
      for (int n = 0; n < 4; ++n)
        acc[m][n] = __builtin_amdgcn_mfma_f32_16x16x32_f16(af[m], bfr[n],
                                                           acc[m][n], 0, 0, 0);
    __builtin_amdgcn_s_setprio(0);
  }

#pragma unroll
  for (int m = 0; m < 4; ++m) {
#pragma unroll
    for (int n = 0; n < 4; ++n) {
      const int gn = n0 + wn + n * 16 + lr;
#pragma unroll
      for (int reg = 0; reg < 4; ++reg) {
        const int gm = m0 + wm + m * 16 + lg * 4 + reg;
        const float v = acc[m][n][reg];
        if constexpr (MODE == 0) {
          const int which = gn >> 11;
          const int head = (gn >> 8) & 7;
          const int d = gn & 255;
          const int b = gm >> 10, t = gm & 1023;
          unsigned short* dst = (which == 0) ? qb : (which == 1) ? kb : vb;
          dst[(((size_t)b * 8 + head) * 1024 + t) * 256 + d] = f2h(v);
        } else {
          outp[(size_t)gm * 2048 + gn] = v + resid[(size_t)gm * 2048 + gn];
        }
      }
    }
  }
}

// ---------------------------------------------------------------- flash attention
// 8 waves x 16 q-rows = 128 q-rows/block; KVBLK=32.
// K: double-buffered LDS (global_load_lds, pre-swizzled source).
// V: single-buffered LDS, staged at iter start, counted vmcnt(4) before PV.
__global__ __launch_bounds__(512, 2) void attn_kernel(
    const unsigned short* __restrict__ qbuf, const unsigned short* __restrict__ kbuf,
    const unsigned short* __restrict__ vT, const int* __restrict__ mask,
    const int* __restrict__ pre, unsigned short* __restrict__ ctx) {
  __shared__ __align__(16) unsigned short klds[2][32 * 256];  // 2 x 16 KB
  __shared__ __align__(16) unsigned short vlds[256 * 32];     // 16 KB
  __shared__ __align__(16) unsigned short plds[8 * 16 * 32];  // 8 KB
  __shared__ int mlds[1024];                                  // 4 KB
  const int tid = threadIdx.x;
  const int w = tid >> 6, l = tid & 63;
  const int lr = l & 15, lg = l >> 4;
  // XCD-chunk swizzle: 512 blocks; the 8 q-blocks of each bh share one XCD.
  const int j = blockIdx.x;
  const int swz = (j & 7) * 64 + (j >> 3);
  const int bh = swz >> 3, qb = swz & 7;
  const int b = bh >> 3, h = bh & 7;
  const int isPre = pre[0];
  const int qrow0 = qb * 128 + w * 16;

  const unsigned short* kbh = kbuf + (size_t)bh * 1024 * 256;
  const unsigned short* vbh = vT + (size_t)bh * 256 * 1024;
  unsigned short* pl = plds + w * 512;

  // mask row -> LDS
  *(int2*)&mlds[tid * 2] = *(const int2*)&mask[b * 1024 + tid * 2];

  // Q fragments (held in registers for all 32 kv steps)
  const unsigned short* qrow =
      qbuf + ((size_t)bh * 1024 + qrow0 + lr) * 256 + lg * 8;
  f16x8 qf[8];
#pragma unroll
  for (int kk = 0; kk < 8; ++kk) qf[kk] = ldh8(qrow + kk * 32);

  // staging lane geometry
  const int krow_in = l >> 5;   // K: row within 2-row issue
  const int ksp = l & 31;       // K: 16B slot within 512B row
  const int vrow_in = l >> 2;   // V: row within 16-row issue
  const int vsp = l & 3;        // V: 16B slot within 64B row

  // prologue: stage K(0) -> klds[0]
#pragma unroll
  for (int ii = 0; ii < 2; ++ii) {
    const int i = w * 2 + ii;
    const int kr = i * 2 + krow_in;
    const unsigned short* ksrc =
        kbh + (size_t)kr * 256 + (((ksp ^ (kr & 7))) << 3);
    GLD_LDS16(ksrc, &klds[0][i * 512]);
  }
  __syncthreads();

  const f32x4 zero = {0.f, 0.f, 0.f, 0.f};
  f32x4 oacc[16];
#pragma unroll
  for (int dt = 0; dt < 16; ++dt) oacc[dt] = zero;
  float mrow[4] = {-1e30f, -1e30f, -1e30f, -1e30f};
  float lrow[4] = {0.f, 0.f, 0.f, 0.f};

  for (int t = 0; t < 32; ++t) {
    const int kv0 = t * 32;
    // ---- stage V(t) (4 issues/wave), then K(t+1) (4 issues/wave, wraps)
#pragma unroll
    for (int ii = 0; ii < 2; ++ii) {
      const int i = w * 2 + ii;
      const int dr = i * 16 + vrow_in;
      const unsigned short* vsrc =
          vbh + (size_t)dr * 1024 + kv0 + ((vsp ^ ((dr >> 1) & 3)) << 3);
      GLD_LDS16(vsrc, &vlds[i * 512]);
    }
    __builtin_amdgcn_sched_barrier(0);
    {
      const int kvn = ((t + 1) & 31) * 32;
#pragma unroll
      for (int ii = 0; ii < 2; ++ii) {
        const int i = w * 2 + ii;
        const int kr = i * 2 + krow_in;
        const unsigned short* ksrc =
            kbh + (size_t)(kvn + kr) * 256 + ((ksp ^ (kr & 7)) << 3);
        GLD_LDS16(ksrc, &klds[(t + 1) & 1][i * 512]);
      }
    }
    __builtin_amdgcn_sched_barrier(0);

    // ---- QK^T from klds[t&1]
    const unsigned short* kcur = klds[t & 1];
    f32x4 sacc[2];
    sacc[0] = zero; sacc[1] = zero;
    __builtin_amdgcn_s_setprio(1);
#pragma unroll
    for (int kk = 0; kk < 8; ++kk) {
#pragma unroll
      for (int n = 0; n < 2; ++n) {
        const int row = n * 16 + lr;
        const f16x8 kf =
            ldh8(&kcur[row * 256 + (((kk * 4 + lg) ^ (row & 7)) << 3)]);
        sacc[n] = __builtin_amdgcn_mfma_f32_16x16x32_f16(qf[kk], kf, sacc[n], 0, 0, 0);
      }
    }
    __builtin_amdgcn_s_setprio(0);

    // ---- mask + online softmax (rows owned by (lg,reg); cols over (n,lr))
    int mv[2];
    mv[0] = mlds[kv0 + lr];
    mv[1] = mlds[kv0 + 16 + lr];
    float sf[4];
#pragma unroll
    for (int reg = 0; reg < 4; ++reg) {
      const int qg = qrow0 + lg * 4 + reg;
      float mx = -3.0e38f;
#pragma unroll
      for (int n = 0; n < 2; ++n) {
        const int kvg = kv0 + n * 16 + lr;
        float s = sacc[n][reg];
        const bool msk = (mv[n] != 0) || (isPre && (kvg > qg));
        s = msk ? -1e9f : s;
        s *= 0.0625f;  // masked_fill THEN scale, matching reference
        sacc[n][reg] = s;
        mx = fmaxf(mx, s);
      }
      mx = fmaxf(mx, __shfl_xor(mx, 1));
      mx = fmaxf(mx, __shfl_xor(mx, 2));
      mx = fmaxf(mx, __shfl_xor(mx, 4));
      mx = fmaxf(mx, __shfl_xor(mx, 8));
      const float mnew = fmaxf(mrow[reg], mx);
      sf[reg] = __expf(mrow[reg] - mnew);
      float ps = 0.f;
#pragma unroll
      for (int n = 0; n < 2; ++n) {
        const float pv = __expf(sacc[n][reg] - mnew);
        sacc[n][reg] = pv;
        ps += pv;
      }
      ps += __shfl_xor(ps, 1);
      ps += __shfl_xor(ps, 2);
      ps += __shfl_xor(ps, 4);
      ps += __shfl_xor(ps, 8);
      lrow[reg] = lrow[reg] * sf[reg] + ps;
      mrow[reg] = mnew;
    }
#pragma unroll
    for (int dt = 0; dt < 16; ++dt) {
      f32x4 o = oacc[dt];
      o[0] *= sf[0]; o[1] *= sf[1]; o[2] *= sf[2]; o[3] *= sf[3];
      oacc[dt] = o;
    }

    // ---- P -> per-wave LDS (swizzled: 4 slots/row, slot ^= (row>>1)&3)
#pragma unroll
    for (int n = 0; n < 2; ++n) {
#pragma unroll
      for (int reg = 0; reg < 4; ++reg) {
        const int row = lg * 4 + reg;
        const int col = n * 16 + lr;
        const int slot = col >> 3;
        pl[row * 32 + (((slot ^ ((row >> 1) & 3)) << 3) | (col & 7))] =
            f2h(sacc[n][reg]);
      }
    }
    asm volatile("s_waitcnt lgkmcnt(0)" ::: "memory");
    __builtin_amdgcn_sched_barrier(0);
    // wait the 4 V-issues (oldest); K(t+1)'s 4 stay in flight
    asm volatile("s_waitcnt vmcnt(4)" ::: "memory");
    __builtin_amdgcn_sched_barrier(0);

    // ---- PV from plds + vlds
    const f16x8 pf = ldh8(&pl[lr * 32 + ((lg ^ ((lr >> 1) & 3)) << 3)]);
    __builtin_amdgcn_s_setprio(1);
#pragma unroll
    for (int dt = 0; dt < 16; ++dt) {
      const int row = dt * 16 + lr;
      const f16x8 vf = ldh8(&vlds[row * 32 + ((lg ^ ((row >> 1) & 3)) << 3)]);
      oacc[dt] = __builtin_amdgcn_mfma_f32_16x16x32_f16(pf, vf, oacc[dt], 0, 0, 0);
    }
    __builtin_amdgcn_s_setprio(0);
    __syncthreads();  // drains remaining vmcnt (K prefetch) + lgkm, then barrier
  }

  float inv[4];
#pragma unroll
  for (int reg = 0; reg < 4; ++reg) inv[reg] = 1.0f / lrow[reg];
#pragma unroll
  for (int dt = 0; dt < 16; ++dt) {
#pragma unroll
    for (int reg = 0; reg < 4; ++reg) {
      const int qg = qrow0 + lg * 4 + reg;
      ctx[((size_t)b * 1024 + qg) * 2048 + h * 256 + dt * 16 + lr] =
          f2h(oacc[dt][reg] * inv[reg]);
    }
  }
}

// ---------------------------------------------------------------- launch
extern "C" void kernel_launch(void* const* d_in, const int* in_sizes, int n_in,
                              void* d_out, int out_size, void* d_ws,
                              size_t ws_size, hipStream_t stream) {
  const float* x_in = (const float*)d_in[0];
  const int* mask = (const int*)d_in[1];
  const float* lnw = (const float*)d_in[2];
  const float* lnb = (const float*)d_in[3];
  const float* qkvw = (const float*)d_in[4];
  const float* ow = (const float*)d_in[5];
  const int* ispre = (const int*)d_in[6];
  float* out = (float*)d_out;
  char* ws = (char*)d_ws;

  const size_t SZ = 33554432;  // 8192*2048*2 bytes
  unsigned short* xln = (unsigned short*)(ws);           // dead after gemm_qkv
  unsigned short* wTq = (unsigned short*)(ws + SZ);      // 25165824
  unsigned short* oT = (unsigned short*)(ws + SZ + 25165824);  // 8388608
  unsigned short* qb;
  unsigned short* kb;
  unsigned short* vb;
  const size_t base = SZ + 25165824 + 8388608;  // 67108864
  if (ws_size >= base + 3 * SZ) {
    qb = (unsigned short*)(ws + base);
    kb = (unsigned short*)(ws + base + SZ);
    vb = (unsigned short*)(ws + base + 2 * SZ);
  } else {
    // fallback: park q/k in d_out (dead before the final GEMM writes it)
    qb = (unsigned short*)d_out;
    kb = qb + SZ / 2;
    vb = (unsigned short*)(ws + base);
  }
  unsigned short* vT = xln;  // alias: xln dead once gemm_qkv is done
  unsigned short* ctxb = vb; // alias: vb dead once transpose_v is done

  ln_kernel<<<8192, 256, 0, stream>>>(x_in, lnw, lnb, xln);
  transpose_w_kernel<<<dim3(192, 64), dim3(32, 8), 0, stream>>>(qkvw, wTq, 2048, 6144);
  transpose_w_kernel<<<dim3(64, 64), dim3(32, 8), 0, stream>>>(ow, oT, 2048, 2048);
  gemm_bt_kernel<0><<<3072, 256, 0, stream>>>(
      xln, wTq, 2048, 48, qb, kb, vb, nullptr, nullptr);
  transpose_v_kernel<<<dim3(8, 32, 64), dim3(32, 8), 0, stream>>>(vb, vT);
  attn_kernel<<<512, 512, 0, stream>>>(qb, kb, vT, mask, ispre, ctxb);
  gemm_bt_kernel<1><<<1024, 256, 0, stream>>>(
      ctxb, oT, 2048, 16, nullptr, nullptr, nullptr, x_in, out);
}

// Round 6
// 655.959 us; speedup vs baseline: 1.4964x; 1.1060x over previous
//
#include <hip/hip_runtime.h>
#include <cstdint>
#include <cstddef>

typedef __attribute__((ext_vector_type(8))) short s16x8;
typedef __attribute__((ext_vector_type(8))) _Float16 f16x8;
typedef __attribute__((ext_vector_type(4))) float f32x4;

__device__ __forceinline__ unsigned short f2h(float f) {
  union { _Float16 h; unsigned short u; } x;
  x.h = (_Float16)f;  // v_cvt_f16_f32, RTNE
  return x.u;
}

__device__ __forceinline__ f16x8 ldh8(const unsigned short* p) {
  union { s16x8 s; f16x8 h; } u;
  u.s = *(const s16x8*)p;
  return u.h;
}

#define GLD_LDS16(g, l)                                                        \
  __builtin_amdgcn_global_load_lds(                                            \
      (const __attribute__((address_space(1))) void*)(g),                      \
      (__attribute__((address_space(3))) void*)(l), 16, 0, 0)

// ---------------------------------------------------------------- LayerNorm
__global__ __launch_bounds__(256) void ln_kernel(
    const float* __restrict__ x, const float* __restrict__ gw,
    const float* __restrict__ gb, unsigned short* __restrict__ y) {
  const int row = blockIdx.x;
  const int t = threadIdx.x;
  const int w = t >> 6, l = t & 63;
  const float* xr = x + (size_t)row * 2048 + t * 8;
  float4 a = *(const float4*)xr;
  float4 c = *(const float4*)(xr + 4);
  float s = a.x + a.y + a.z + a.w + c.x + c.y + c.z + c.w;
  float q = a.x * a.x + a.y * a.y + a.z * a.z + a.w * a.w +
            c.x * c.x + c.y * c.y + c.z * c.z + c.w * c.w;
#pragma unroll
  for (int off = 1; off < 64; off <<= 1) {
    s += __shfl_xor(s, off);
    q += __shfl_xor(q, off);
  }
  __shared__ float red[8];
  if (l == 0) { red[w] = s; red[4 + w] = q; }
  __syncthreads();
  s = red[0] + red[1] + red[2] + red[3];
  q = red[4] + red[5] + red[6] + red[7];
  const float mu = s * (1.0f / 2048.0f);
  const float var = q * (1.0f / 2048.0f) - mu * mu;
  const float rs = rsqrtf(var + 1e-8f);
  float4 w0 = *(const float4*)(gw + t * 8);
  float4 w1 = *(const float4*)(gw + t * 8 + 4);
  float4 b0 = *(const float4*)(gb + t * 8);
  float4 b1 = *(const float4*)(gb + t * 8 + 4);
  s16x8 ov;
  ov[0] = (short)f2h((a.x - mu) * rs * w0.x + b0.x);
  ov[1] = (short)f2h((a.y - mu) * rs * w0.y + b0.y);
  ov[2] = (short)f2h((a.z - mu) * rs * w0.z + b0.z);
  ov[3] = (short)f2h((a.w - mu) * rs * w0.w + b0.w);
  ov[4] = (short)f2h((c.x - mu) * rs * w1.x + b1.x);
  ov[5] = (short)f2h((c.y - mu) * rs * w1.y + b1.y);
  ov[6] = (short)f2h((c.z - mu) * rs * w1.z + b1.z);
  ov[7] = (short)f2h((c.w - mu) * rs * w1.w + b1.w);
  *(s16x8*)(y + (size_t)row * 2048 + t * 8) = ov;
}

// -------------------------------------- weight transpose f32[R][C] -> f16[C][R]
__global__ __launch_bounds__(256) void transpose_w_kernel(
    const float* __restrict__ in, unsigned short* __restrict__ out,
    int R, int C) {
  __shared__ float tile[32][33];
  const int c0 = blockIdx.x * 32, r0 = blockIdx.y * 32;
  const int x = threadIdx.x, y = threadIdx.y;
#pragma unroll
  for (int k = 0; k < 4; ++k)
    tile[y + k * 8][x] = in[(size_t)(r0 + y + k * 8) * C + c0 + x];
  __syncthreads();
#pragma unroll
  for (int k = 0; k < 4; ++k)
    out[(size_t)(c0 + y + k * 8) * R + r0 + x] = f2h(tile[x][y + k * 8]);
}

// -------------------------------------- V transpose f16 [bh][1024][256] -> [bh][256][1024]
__global__ __launch_bounds__(256) void transpose_v_kernel(
    const unsigned short* __restrict__ in, unsigned short* __restrict__ out) {
  __shared__ unsigned short tile[32][33];
  const int bh = blockIdx.z;
  const int d0 = blockIdx.x * 32, t0 = blockIdx.y * 32;
  const unsigned short* ip = in + (size_t)bh * 1024 * 256;
  unsigned short* op = out + (size_t)bh * 256 * 1024;
  const int x = threadIdx.x, y = threadIdx.y;
#pragma unroll
  for (int k = 0; k < 4; ++k)
    tile[y + k * 8][x] = ip[(size_t)(t0 + y + k * 8) * 256 + d0 + x];
  __syncthreads();
#pragma unroll
  for (int k = 0; k < 4; ++k)
    op[(size_t)(d0 + y + k * 8) * 1024 + t0 + x] = tile[x][y + k * 8];
}

// ---------------------------------------------------------------- 256x256 8-phase GEMM
// A row-major [M][K], Bt row-major [N][K]. 512 thr = 8 waves (2M x 4N).
// K-tile = 64 split in 2 k-halves; stage unit = one tensor x one k-half
// (256 rows x 32 k) staged linearly (global_load_lds, pre-swizzled source),
// double-buffered. 4 phases/tile, 16 MFMA/phase, counted vmcnt(4) at the
// close of phases 1 and 3 only (never drains in the main loop).
__device__ __forceinline__ void stage256x32(const unsigned short* gbase_k, int ldg,
                                            unsigned short* region, int w, int l) {
  // LDS[row][phys_slot] = G[row][phys_slot ^ ((row>>1)&3)]  (16B slots)
#pragma unroll
  for (int i = 0; i < 2; ++i) {
    const int chunk = w * 2 + i;            // 16 chunks x 16 rows
    const int r = chunk * 16 + (l >> 2);
    const unsigned short* src =
        gbase_k + (size_t)r * ldg + (((l & 3) ^ ((l >> 3) & 3)) << 3);
    GLD_LDS16(src, region + chunk * 512);
  }
}

#define LGKM0_SB                                                \
  asm volatile("s_waitcnt lgkmcnt(0)" ::: "memory");            \
  __builtin_amdgcn_sched_barrier(0)

template <int MODE>
__global__ __launch_bounds__(512, 2) void gemm256_kernel(
    const unsigned short* __restrict__ A, const unsigned short* __restrict__ Bt,
    const int K, const int NB,
    unsigned short* __restrict__ qb, unsigned short* __restrict__ kb,
    unsigned short* __restrict__ vb,
    const float* __restrict__ resid, float* __restrict__ outp) {
  __shared__ __align__(16) unsigned short ldsA[2][2][256 * 32];  // 64 KB
  __shared__ __align__(16) unsigned short ldsB[2][2][256 * 32];  // 64 KB
  const int tid = threadIdx.x;
  const int w = tid >> 6, l = tid & 63;
  const int lr = l & 15, lg = l >> 4;
  const int wm = w >> 2, wn = w & 3;  // 2 x 4 wave grid
  // XCD-chunk swizzle (bijective: gridDim.x % 8 == 0)
  const int flat = blockIdx.x;
  const int cpx = gridDim.x >> 3;
  const int swz = (flat & 7) * cpx + (flat >> 3);
  const int m0 = (swz / NB) * 256, n0 = (swz % NB) * 256;
  const unsigned short* Abase = A + (size_t)m0 * K;
  const unsigned short* Bbase = Bt + (size_t)n0 * K;

  const f32x4 zero = {0.f, 0.f, 0.f, 0.f};
  f32x4 acc[8][4];
#pragma unroll
  for (int m = 0; m < 8; ++m)
#pragma unroll
    for (int n = 0; n < 4; ++n) acc[m][n] = zero;

  // prologue: stage tile 0 in unit order A-k0, B-k0, A-k1, B-k1
  stage256x32(Abase, K, &ldsA[0][0][0], w, l);
  stage256x32(Bbase, K, &ldsB[0][0][0], w, l);
  stage256x32(Abase + 32, K, &ldsA[0][1][0], w, l);
  stage256x32(Bbase + 32, K, &ldsB[0][1][0], w, l);
  asm volatile("s_waitcnt vmcnt(4)" ::: "memory");  // A-k0,B-k0 landed
  __builtin_amdgcn_s_barrier();

  const int NT = K >> 6;
  for (int t = 0; t < NT; ++t) {
    const int cur = t & 1, nxt = cur ^ 1;
    const int ktn = (t + 1 < NT) ? ((t + 1) << 6) : 0;  // clamp keeps counts uniform
    f16x8 af[8], b0, b1;
    // ---------------- phase 0: k-half 0, n-half 0
    {
      const unsigned short* Ar = &ldsA[cur][0][0];
      const unsigned short* Br = &ldsB[cur][0][0];
#pragma unroll
      for (int m = 0; m < 8; ++m) {
        const int R = wm * 128 + m * 16 + lr;
        af[m] = ldh8(&Ar[R * 32 + ((lg ^ ((R >> 1) & 3)) << 3)]);
      }
      { const int R = wn * 64 + lr;      b0 = ldh8(&Br[R * 32 + ((lg ^ ((R >> 1) & 3)) << 3)]); }
      { const int R = wn * 64 + 16 + lr; b1 = ldh8(&Br[R * 32 + ((lg ^ ((R >> 1) & 3)) << 3)]); }
      stage256x32(Abase + ktn, K, &ldsA[nxt][0][0], w, l);
      __builtin_amdgcn_s_barrier();
      LGKM0_SB;
      __builtin_amdgcn_s_setprio(1);
#pragma unroll
      for (int m = 0; m < 8; ++m) {
        acc[m][0] = __builtin_amdgcn_mfma_f32_16x16x32_f16(af[m], b0, acc[m][0], 0, 0, 0);
        acc[m][1] = __builtin_amdgcn_mfma_f32_16x16x32_f16(af[m], b1, acc[m][1], 0, 0, 0);
      }
      __builtin_amdgcn_s_setprio(0);
      __builtin_amdgcn_sched_barrier(0);
      __builtin_amdgcn_s_barrier();
    }
    // ---------------- phase 1: k-half 0, n-half 1
    {
      const unsigned short* Br = &ldsB[cur][0][0];
      { const int R = wn * 64 + 32 + lr; b0 = ldh8(&Br[R * 32 + ((lg ^ ((R >> 1) & 3)) << 3)]); }
      { const int R = wn * 64 + 48 + lr; b1 = ldh8(&Br[R * 32 + ((lg ^ ((R >> 1) & 3)) << 3)]); }
      stage256x32(Bbase + ktn, K, &ldsB[nxt][0][0], w, l);
      __builtin_amdgcn_s_barrier();
      LGKM0_SB;
      __builtin_amdgcn_s_setprio(1);
#pragma unroll
      for (int m = 0; m < 8; ++m) {
        acc[m][2] = __builtin_amdgcn_mfma_f32_16x16x32_f16(af[m], b0, acc[m][2], 0, 0, 0);
        acc[m][3] = __builtin_amdgcn_mfma_f32_16x16x32_f16(af[m], b1, acc[m][3], 0, 0, 0);
      }
      __builtin_amdgcn_s_setprio(0);
      __builtin_amdgcn_sched_barrier(0);
      asm volatile("s_waitcnt vmcnt(4)" ::: "memory");  // A-k1(t),B-k1(t) landed
      __builtin_amdgcn_s_barrier();
    }
    // ---------------- phase 2: k-half 1, n-half 0
    {
      const unsigned short* Ar = &ldsA[cur][1][0];
      const unsigned short* Br = &ldsB[cur][1][0];
#pragma unroll
      for (int m = 0; m < 8; ++m) {
        const int R = wm * 128 + m * 16 + lr;
        af[m] = ldh8(&Ar[R * 32 + ((lg ^ ((R >> 1) & 3)) << 3)]);
      }
      { const int R = wn * 64 + lr;      b0 = ldh8(&Br[R * 32 + ((lg ^ ((R >> 1) & 3)) << 3)]); }
      { const int R = wn * 64 + 16 + lr; b1 = ldh8(&Br[R * 32 + ((lg ^ ((R >> 1) & 3)) << 3)]); }
      stage256x32(Abase + ktn + 32, K, &ldsA[nxt][1][0], w, l);
      __builtin_amdgcn_s_barrier();
      LGKM0_SB;
      __builtin_amdgcn_s_setprio(1);
#pragma unroll
      for (int m = 0; m < 8; ++m) {
        acc[m][0] = __builtin_amdgcn_mfma_f32_16x16x32_f16(af[m], b0, acc[m][0], 0, 0, 0);
        acc[m][1] = __builtin_amdgcn_mfma_f32_16x16x32_f16(af[m], b1, acc[m][1], 0, 0, 0);
      }
      __builtin_amdgcn_s_setprio(0);
      __builtin_amdgcn_sched_barrier(0);
      __builtin_amdgcn_s_barrier();
    }
    // ---------------- phase 3: k-half 1, n-half 1
    {
      const unsigned short* Br = &ldsB[cur][1][0];
      { const int R = wn * 64 + 32 + lr; b0 = ldh8(&Br[R * 32 + ((lg ^ ((R >> 1) & 3)) << 3)]); }
      { const int R = wn * 64 + 48 + lr; b1 = ldh8(&Br[R * 32 + ((lg ^ ((R >> 1) & 3)) << 3)]); }
      stage256x32(Bbase + ktn + 32, K, &ldsB[nxt][1][0], w, l);
      __builtin_amdgcn_s_barrier();
      LGKM0_SB;
      __builtin_amdgcn_s_setprio(1);
#pragma unroll
      for (int m = 0; m < 8; ++m) {
        acc[m][2] = __builtin_amdgcn_mfma_f32_16x16x32_f16(af[m], b0, acc[m][2], 0, 0, 0);
        acc[m][3] = __builtin_amdgcn_mfma_f32_16x16x32_f16(af[m], b1, acc[m][3], 0, 0, 0);
      }
      __builtin_amdgcn_s_setprio(0);
      __builtin_amdgcn_sched_barrier(0);
      asm volatile("s_waitcnt vmcnt(4)" ::: "memory");  // A-k0(t+1),B-k0(t+1) landed
      __builtin_amdgcn_s_barrier();
    }
  }
  asm volatile("s_waitcnt vmcnt(0)" ::: "memory");  // drain dangling prefetch

#pragma unroll
  for (int m = 0; m < 8; ++m) {
#pragma unroll
    for (int n = 0; n < 4; ++n) {
      const int gn = n0 + wn * 64 + n * 16 + lr;
#pragma unroll
      for (int reg = 0; reg < 4; ++reg) {
        const int gm = m0 + wm * 128 + m * 16 + lg * 4 + reg;
        const float v = acc[m][n][reg];
        if constexpr (MODE == 0) {
          const int which = gn >> 11;
          const int head = (gn >> 8) & 7;
          const int d = gn & 255;
          const int b = gm >> 10, t = gm & 1023;
          unsigned short* dst = (which == 0) ? qb : (which == 1) ? kb : vb;
          dst[(((size_t)b * 8 + head) * 1024 + t) * 256 + d] = f2h(v);
        } else {
          outp[(size_t)gm * 2048 + gn] = v + resid[(size_t)gm * 2048 + gn];
        }
      }
    }
  }
}

// ---------------------------------------------------------------- flash attention
// 8 waves x 16 q-rows = 128 q-rows/block; KVBLK=32.
// K: double-buffered LDS (global_load_lds, pre-swizzled source).
// V: single-buffered LDS, staged at iter start, counted vmcnt(4) before PV.
__global__ __launch_bounds__(512, 2) void attn_kernel(
    const unsigned short* __restrict__ qbuf, const unsigned short* __restrict__ kbuf,
    const unsigned short* __restrict__ vT, const int* __restrict__ mask,
    const int* __restrict__ pre, unsigned short* __restrict__ ctx) {
  __shared__ __align__(16) unsigned short klds[2][32 * 256];  // 2 x 16 KB
  __shared__ __align__(16) unsigned short vlds[256 * 32];     // 16 KB
  __shared__ __align__(16) unsigned short plds[8 * 16 * 32];  // 8 KB
  __shared__ int mlds[1024];                                  // 4 KB
  const int tid = threadIdx.x;
  const int w = tid >> 6, l = tid & 63;
  const int lr = l & 15, lg = l >> 4;
  // XCD-chunk swizzle: 512 blocks; the 8 q-blocks of each bh share one XCD.
  const int j = blockIdx.x;
  const int swz = (j & 7) * 64 + (j >> 3);
  const int bh = swz >> 3, qb = swz & 7;
  const int b = bh >> 3, h = bh & 7;
  const int isPre = pre[0];
  const int qrow0 = qb * 128 + w * 16;

  const unsigned short* kbh = kbuf + (size_t)bh * 1024 * 256;
  const unsigned short* vbh = vT + (size_t)bh * 256 * 1024;
  unsigned short* pl = plds + w * 512;

  // mask row -> LDS
  *(int2*)&mlds[tid * 2] = *(const int2*)&mask[b * 1024 + tid * 2];

  // Q fragments (held in registers for all 32 kv steps)
  const unsigned short* qrow =
      qbuf + ((size_t)bh * 1024 + qrow0 + lr) * 256 + lg * 8;
  f16x8 qf[8];
#pragma unroll
  for (int kk = 0; kk < 8; ++kk) qf[kk] = ldh8(qrow + kk * 32);

  // staging lane geometry
  const int krow_in = l >> 5;   // K: row within 2-row issue
  const int ksp = l & 31;       // K: 16B slot within 512B row
  const int vrow_in = l >> 2;   // V: row within 16-row issue
  const int vsp = l & 3;        // V: 16B slot within 64B row

  // prologue: stage K(0) -> klds[0]
#pragma unroll
  for (int ii = 0; ii < 2; ++ii) {
    const int i = w * 2 + ii;
    const int kr = i * 2 + krow_in;
    const unsigned short* ksrc =
        kbh + (size_t)kr * 256 + (((ksp ^ (kr & 7))) << 3);
    GLD_LDS16(ksrc, &klds[0][i * 512]);
  }
  __syncthreads();

  const f32x4 zero = {0.f, 0.f, 0.f, 0.f};
  f32x4 oacc[16];
#pragma unroll
  for (int dt = 0; dt < 16; ++dt) oacc[dt] = zero;
  float mrow[4] = {-1e30f, -1e30f, -1e30f, -1e30f};
  float lrow[4] = {0.f, 0.f, 0.f, 0.f};

  for (int t = 0; t < 32; ++t) {
    const int kv0 = t * 32;
    // ---- stage V(t) (4 issues/wave), then K(t+1) (4 issues/wave, wraps)
#pragma unroll
    for (int ii = 0; ii < 2; ++ii) {
      const int i = w * 2 + ii;
      const int dr = i * 16 + vrow_in;
      const unsigned short* vsrc =
          vbh + (size_t)dr * 1024 + kv0 + ((vsp ^ ((dr >> 1) & 3)) << 3);
      GLD_LDS16(vsrc, &vlds[i * 512]);
    }
    __builtin_amdgcn_sched_barrier(0);
    {
      const int kvn = ((t + 1) & 31) * 32;
#pragma unroll
      for (int ii = 0; ii < 2; ++ii) {
        const int i = w * 2 + ii;
        const int kr = i * 2 + krow_in;
        const unsigned short* ksrc =
            kbh + (size_t)(kvn + kr) * 256 + ((ksp ^ (kr & 7)) << 3);
        GLD_LDS16(ksrc, &klds[(t + 1) & 1][i * 512]);
      }
    }
    __builtin_amdgcn_sched_barrier(0);

    // ---- QK^T from klds[t&1]
    const unsigned short* kcur = klds[t & 1];
    f32x4 sacc[2];
    sacc[0] = zero; sacc[1] = zero;
    __builtin_amdgcn_s_setprio(1);
#pragma unroll
    for (int kk = 0; kk < 8; ++kk) {
#pragma unroll
      for (int n = 0; n < 2; ++n) {
        const int row = n * 16 + lr;
        const f16x8 kf =
            ldh8(&kcur[row * 256 + (((kk * 4 + lg) ^ (row & 7)) << 3)]);
        sacc[n] = __builtin_amdgcn_mfma_f32_16x16x32_f16(qf[kk], kf, sacc[n], 0, 0, 0);
      }
    }
    __builtin_amdgcn_s_setprio(0);

    // ---- mask + online softmax (rows owned by (lg,reg); cols over (n,lr))
    int mv[2];
    mv[0] = mlds[kv0 + lr];
    mv[1] = mlds[kv0 + 16 + lr];
    float sf[4];
#pragma unroll
    for (int reg = 0; reg < 4; ++reg) {
      const int qg = qrow0 + lg * 4 + reg;
      float mx = -3.0e38f;
#pragma unroll
      for (int n = 0; n < 2; ++n) {
        const int kvg = kv0 + n * 16 + lr;
        float s = sacc[n][reg];
        const bool msk = (mv[n] != 0) || (isPre && (kvg > qg));
        s = msk ? -1e9f : s;
        s *= 0.0625f;  // masked_fill THEN scale, matching reference
        sacc[n][reg] = s;
        mx = fmaxf(mx, s);
      }
      mx = fmaxf(mx, __shfl_xor(mx, 1));
      mx = fmaxf(mx, __shfl_xor(mx, 2));
      mx = fmaxf(mx, __shfl_xor(mx, 4));
      mx = fmaxf(mx, __shfl_xor(mx, 8));
      const float mnew = fmaxf(mrow[reg], mx);
      sf[reg] = __expf(mrow[reg] - mnew);
      float ps = 0.f;
#pragma unroll
      for (int n = 0; n < 2; ++n) {
        const float pv = __expf(sacc[n][reg] - mnew);
        sacc[n][reg] = pv;
        ps += pv;
      }
      ps += __shfl_xor(ps, 1);
      ps += __shfl_xor(ps, 2);
      ps += __shfl_xor(ps, 4);
      ps += __shfl_xor(ps, 8);
      lrow[reg] = lrow[reg] * sf[reg] + ps;
      mrow[reg] = mnew;
    }
#pragma unroll
    for (int dt = 0; dt < 16; ++dt) {
      f32x4 o = oacc[dt];
      o[0] *= sf[0]; o[1] *= sf[1]; o[2] *= sf[2]; o[3] *= sf[3];
      oacc[dt] = o;
    }

    // ---- P -> per-wave LDS (swizzled: 4 slots/row, slot ^= (row>>1)&3)
#pragma unroll
    for (int n = 0; n < 2; ++n) {
#pragma unroll
      for (int reg = 0; reg < 4; ++reg) {
        const int row = lg * 4 + reg;
        const int col = n * 16 + lr;
        const int slot = col >> 3;
        pl[row * 32 + (((slot ^ ((row >> 1) & 3)) << 3) | (col & 7))] =
            f2h(sacc[n][reg]);
      }
    }
    asm volatile("s_waitcnt lgkmcnt(0)" ::: "memory");
    __builtin_amdgcn_sched_barrier(0);
    // wait the 4 V-issues (oldest); K(t+1)'s 4 stay in flight
    asm volatile("s_waitcnt vmcnt(4)" ::: "memory");
    __builtin_amdgcn_sched_barrier(0);

    // ---- PV from plds + vlds
    const f16x8 pf = ldh8(&pl[lr * 32 + ((lg ^ ((lr >> 1) & 3)) << 3)]);
    __builtin_amdgcn_s_setprio(1);
#pragma unroll
    for (int dt = 0; dt < 16; ++dt) {
      const int row = dt * 16 + lr;
      const f16x8 vf = ldh8(&vlds[row * 32 + ((lg ^ ((row >> 1) & 3)) << 3)]);
      oacc[dt] = __builtin_amdgcn_mfma_f32_16x16x32_f16(pf, vf, oacc[dt], 0, 0, 0);
    }
    __builtin_amdgcn_s_setprio(0);
    __syncthreads();  // drains remaining vmcnt (K prefetch) + lgkm, then barrier
  }

  float inv[4];
#pragma unroll
  for (int reg = 0; reg < 4; ++reg) inv[reg] = 1.0f / lrow[reg];
#pragma unroll
  for (int dt = 0; dt < 16; ++dt) {
#pragma unroll
    for (int reg = 0; reg < 4; ++reg) {
      const int qg = qrow0 + lg * 4 + reg;
      ctx[((size_t)b * 1024 + qg) * 2048 + h * 256 + dt * 16 + lr] =
          f2h(oacc[dt][reg] * inv[reg]);
    }
  }
}

// ---------------------------------------------------------------- launch
extern "C" void kernel_launch(void* const* d_in, const int* in_sizes, int n_in,
                              void* d_out, int out_size, void* d_ws,
                              size_t ws_size, hipStream_t stream) {
  const float* x_in = (const float*)d_in[0];
  const int* mask = (const int*)d_in[1];
  const float* lnw = (const float*)d_in[2];
  const float* lnb = (const float*)d_in[3];
  const float* qkvw = (const float*)d_in[4];
  const float* ow = (const float*)d_in[5];
  const int* ispre = (const int*)d_in[6];
  float* out = (float*)d_out;
  char* ws = (char*)d_ws;

  const size_t SZ = 33554432;  // 8192*2048*2 bytes
  unsigned short* xln = (unsigned short*)(ws);           // dead after gemm_qkv
  unsigned short* wTq = (unsigned short*)(ws + SZ);      // 25165824
  unsigned short* oT = (unsigned short*)(ws + SZ + 25165824);  // 8388608
  unsigned short* qb;
  unsigned short* kb;
  unsigned short* vb;
  const size_t base = SZ + 25165824 + 8388608;  // 67108864
  if (ws_size >= base + 3 * SZ) {
    qb = (unsigned short*)(ws + base);
    kb = (unsigned short*)(ws + base + SZ);
    vb = (unsigned short*)(ws + base + 2 * SZ);
  } else {
    // fallback: park q/k in d_out (dead before the final GEMM writes it)
    qb = (unsigned short*)d_out;
    kb = qb + SZ / 2;
    vb = (unsigned short*)(ws + base);
  }
  unsigned short* vT = xln;  // alias: xln dead once gemm_qkv is done
  unsigned short* ctxb = vb; // alias: vb dead once transpose_v is done

  ln_kernel<<<8192, 256, 0, stream>>>(x_in, lnw, lnb, xln);
  transpose_w_kernel<<<dim3(192, 64), dim3(32, 8), 0, stream>>>(qkvw, wTq, 2048, 6144);
  transpose_w_kernel<<<dim3(64, 64), dim3(32, 8), 0, stream>>>(ow, oT, 2048, 2048);
  gemm256_kernel<0><<<768, 512, 0, stream>>>(
      xln, wTq, 2048, 24, qb, kb, vb, nullptr, nullptr);
  transpose_v_kernel<<<dim3(8, 32, 64), dim3(32, 8), 0, stream>>>(vb, vT);
  attn_kernel<<<512, 512, 0, stream>>>(qb, kb, vT, mask, ispre, ctxb);
  gemm256_kernel<1><<<256, 512, 0, stream>>>(
      ctxb, oT, 2048, 8, nullptr, nullptr, nullptr, x_in, out);
}

// Round 7
// 604.309 us; speedup vs baseline: 1.6242x; 1.0855x over previous
//
#include <hip/hip_runtime.h>
#include <cstdint>
#include <cstddef>

typedef __attribute__((ext_vector_type(8))) short s16x8;
typedef __attribute__((ext_vector_type(8))) _Float16 f16x8;
typedef __attribute__((ext_vector_type(4))) float f32x4;

__device__ __forceinline__ unsigned short f2h(float f) {
  union { _Float16 h; unsigned short u; } x;
  x.h = (_Float16)f;  // v_cvt_f16_f32, RTNE
  return x.u;
}

__device__ __forceinline__ f16x8 ldh8(const unsigned short* p) {
  union { s16x8 s; f16x8 h; } u;
  u.s = *(const s16x8*)p;
  return u.h;
}

#define GLD_LDS16(g, l)                                                        \
  __builtin_amdgcn_global_load_lds(                                            \
      (const __attribute__((address_space(1))) void*)(g),                      \
      (__attribute__((address_space(3))) void*)(l), 16, 0, 0)

// ---------------------------------------------------------------- LayerNorm
__global__ __launch_bounds__(256) void ln_kernel(
    const float* __restrict__ x, const float* __restrict__ gw,
    const float* __restrict__ gb, unsigned short* __restrict__ y) {
  const int row = blockIdx.x;
  const int t = threadIdx.x;
  const int w = t >> 6, l = t & 63;
  const float* xr = x + (size_t)row * 2048 + t * 8;
  float4 a = *(const float4*)xr;
  float4 c = *(const float4*)(xr + 4);
  float s = a.x + a.y + a.z + a.w + c.x + c.y + c.z + c.w;
  float q = a.x * a.x + a.y * a.y + a.z * a.z + a.w * a.w +
            c.x * c.x + c.y * c.y + c.z * c.z + c.w * c.w;
#pragma unroll
  for (int off = 1; off < 64; off <<= 1) {
    s += __shfl_xor(s, off);
    q += __shfl_xor(q, off);
  }
  __shared__ float red[8];
  if (l == 0) { red[w] = s; red[4 + w] = q; }
  __syncthreads();
  s = red[0] + red[1] + red[2] + red[3];
  q = red[4] + red[5] + red[6] + red[7];
  const float mu = s * (1.0f / 2048.0f);
  const float var = q * (1.0f / 2048.0f) - mu * mu;
  const float rs = rsqrtf(var + 1e-8f);
  float4 w0 = *(const float4*)(gw + t * 8);
  float4 w1 = *(const float4*)(gw + t * 8 + 4);
  float4 b0 = *(const float4*)(gb + t * 8);
  float4 b1 = *(const float4*)(gb + t * 8 + 4);
  s16x8 ov;
  ov[0] = (short)f2h((a.x - mu) * rs * w0.x + b0.x);
  ov[1] = (short)f2h((a.y - mu) * rs * w0.y + b0.y);
  ov[2] = (short)f2h((a.z - mu) * rs * w0.z + b0.z);
  ov[3] = (short)f2h((a.w - mu) * rs * w0.w + b0.w);
  ov[4] = (short)f2h((c.x - mu) * rs * w1.x + b1.x);
  ov[5] = (short)f2h((c.y - mu) * rs * w1.y + b1.y);
  ov[6] = (short)f2h((c.z - mu) * rs * w1.z + b1.z);
  ov[7] = (short)f2h((c.w - mu) * rs * w1.w + b1.w);
  *(s16x8*)(y + (size_t)row * 2048 + t * 8) = ov;
}

// -------------------------------------- weight transpose f32[R][C] -> f16[C][R]
__global__ __launch_bounds__(256) void transpose_w_kernel(
    const float* __restrict__ in, unsigned short* __restrict__ out,
    int R, int C) {
  __shared__ float tile[32][33];
  const int c0 = blockIdx.x * 32, r0 = blockIdx.y * 32;
  const int x = threadIdx.x, y = threadIdx.y;
#pragma unroll
  for (int k = 0; k < 4; ++k)
    tile[y + k * 8][x] = in[(size_t)(r0 + y + k * 8) * C + c0 + x];
  __syncthreads();
#pragma unroll
  for (int k = 0; k < 4; ++k)
    out[(size_t)(c0 + y + k * 8) * R + r0 + x] = f2h(tile[x][y + k * 8]);
}

// -------------------------------------- V transpose f16 [bh][1024][256] -> [bh][256][1024]
__global__ __launch_bounds__(256) void transpose_v_kernel(
    const unsigned short* __restrict__ in, unsigned short* __restrict__ out) {
  __shared__ unsigned short tile[32][33];
  const int bh = blockIdx.z;
  const int d0 = blockIdx.x * 32, t0 = blockIdx.y * 32;
  const unsigned short* ip = in + (size_t)bh * 1024 * 256;
  unsigned short* op = out + (size_t)bh * 256 * 1024;
  const int x = threadIdx.x, y = threadIdx.y;
#pragma unroll
  for (int k = 0; k < 4; ++k)
    tile[y + k * 8][x] = ip[(size_t)(t0 + y + k * 8) * 256 + d0 + x];
  __syncthreads();
#pragma unroll
  for (int k = 0; k < 4; ++k)
    op[(size_t)(d0 + y + k * 8) * 1024 + t0 + x] = tile[x][y + k * 8];
}

// ---------------------------------------------------------------- 256x256 8-phase GEMM
// (unchanged from round 6 — verified working)
__device__ __forceinline__ void stage256x32(const unsigned short* gbase_k, int ldg,
                                            unsigned short* region, int w, int l) {
  // LDS[row][phys_slot] = G[row][phys_slot ^ ((row>>1)&3)]  (16B slots)
#pragma unroll
  for (int i = 0; i < 2; ++i) {
    const int chunk = w * 2 + i;            // 16 chunks x 16 rows
    const int r = chunk * 16 + (l >> 2);
    const unsigned short* src =
        gbase_k + (size_t)r * ldg + (((l & 3) ^ ((l >> 3) & 3)) << 3);
    GLD_LDS16(src, region + chunk * 512);
  }
}

#define LGKM0_SB                                                \
  asm volatile("s_waitcnt lgkmcnt(0)" ::: "memory");            \
  __builtin_amdgcn_sched_barrier(0)

template <int MODE>
__global__ __launch_bounds__(512, 2) void gemm256_kernel(
    const unsigned short* __restrict__ A, const unsigned short* __restrict__ Bt,
    const int K, const int NB,
    unsigned short* __restrict__ qb, unsigned short* __restrict__ kb,
    unsigned short* __restrict__ vb,
    const float* __restrict__ resid, float* __restrict__ outp) {
  __shared__ __align__(16) unsigned short ldsA[2][2][256 * 32];  // 64 KB
  __shared__ __align__(16) unsigned short ldsB[2][2][256 * 32];  // 64 KB
  const int tid = threadIdx.x;
  const int w = tid >> 6, l = tid & 63;
  const int lr = l & 15, lg = l >> 4;
  const int wm = w >> 2, wn = w & 3;  // 2 x 4 wave grid
  // XCD-chunk swizzle (bijective: gridDim.x % 8 == 0)
  const int flat = blockIdx.x;
  const int cpx = gridDim.x >> 3;
  const int swz = (flat & 7) * cpx + (flat >> 3);
  const int m0 = (swz / NB) * 256, n0 = (swz % NB) * 256;
  const unsigned short* Abase = A + (size_t)m0 * K;
  const unsigned short* Bbase = Bt + (size_t)n0 * K;

  const f32x4 zero = {0.f, 0.f, 0.f, 0.f};
  f32x4 acc[8][4];
#pragma unroll
  for (int m = 0; m < 8; ++m)
#pragma unroll
    for (int n = 0; n < 4; ++n) acc[m][n] = zero;

  // prologue: stage tile 0 in unit order A-k0, B-k0, A-k1, B-k1
  stage256x32(Abase, K, &ldsA[0][0][0], w, l);
  stage256x32(Bbase, K, &ldsB[0][0][0], w, l);
  stage256x32(Abase + 32, K, &ldsA[0][1][0], w, l);
  stage256x32(Bbase + 32, K, &ldsB[0][1][0], w, l);
  asm volatile("s_waitcnt vmcnt(4)" ::: "memory");  // A-k0,B-k0 landed
  __builtin_amdgcn_s_barrier();

  const int NT = K >> 6;
  for (int t = 0; t < NT; ++t) {
    const int cur = t & 1, nxt = cur ^ 1;
    const int ktn = (t + 1 < NT) ? ((t + 1) << 6) : 0;  // clamp keeps counts uniform
    f16x8 af[8], b0, b1;
    // ---------------- phase 0: k-half 0, n-half 0
    {
      const unsigned short* Ar = &ldsA[cur][0][0];
      const unsigned short* Br = &ldsB[cur][0][0];
#pragma unroll
      for (int m = 0; m < 8; ++m) {
        const int R = wm * 128 + m * 16 + lr;
        af[m] = ldh8(&Ar[R * 32 + ((lg ^ ((R >> 1) & 3)) << 3)]);
      }
      { const int R = wn * 64 + lr;      b0 = ldh8(&Br[R * 32 + ((lg ^ ((R >> 1) & 3)) << 3)]); }
      { const int R = wn * 64 + 16 + lr; b1 = ldh8(&Br[R * 32 + ((lg ^ ((R >> 1) & 3)) << 3)]); }
      stage256x32(Abase + ktn, K, &ldsA[nxt][0][0], w, l);
      __builtin_amdgcn_s_barrier();
      LGKM0_SB;
      __builtin_amdgcn_s_setprio(1);
#pragma unroll
      for (int m = 0; m < 8; ++m) {
        acc[m][0] = __builtin_amdgcn_mfma_f32_16x16x32_f16(af[m], b0, acc[m][0], 0, 0, 0);
        acc[m][1] = __builtin_amdgcn_mfma_f32_16x16x32_f16(af[m], b1, acc[m][1], 0, 0, 0);
      }
      __builtin_amdgcn_s_setprio(0);
      __builtin_amdgcn_sched_barrier(0);
      __builtin_amdgcn_s_barrier();
    }
    // ---------------- phase 1: k-half 0, n-half 1
    {
      const unsigned short* Br = &ldsB[cur][0][0];
      { const int R = wn * 64 + 32 + lr; b0 = ldh8(&Br[R * 32 + ((lg ^ ((R >> 1) & 3)) << 3)]); }
      { const int R = wn * 64 + 48 + lr; b1 = ldh8(&Br[R * 32 + ((lg ^ ((R >> 1) & 3)) << 3)]); }
      stage256x32(Bbase + ktn, K, &ldsB[nxt][0][0], w, l);
      __builtin_amdgcn_s_barrier();
      LGKM0_SB;
      __builtin_amdgcn_s_setprio(1);
#pragma unroll
      for (int m = 0; m < 8; ++m) {
        acc[m][2] = __builtin_amdgcn_mfma_f32_16x16x32_f16(af[m], b0, acc[m][2], 0, 0, 0);
        acc[m][3] = __builtin_amdgcn_mfma_f32_16x16x32_f16(af[m], b1, acc[m][3], 0, 0, 0);
      }
      __builtin_amdgcn_s_setprio(0);
      __builtin_amdgcn_sched_barrier(0);
      asm volatile("s_waitcnt vmcnt(4)" ::: "memory");  // A-k1(t),B-k1(t) landed
      __builtin_amdgcn_s_barrier();
    }
    // ---------------- phase 2: k-half 1, n-half 0
    {
      const unsigned short* Ar = &ldsA[cur][1][0];
      const unsigned short* Br = &ldsB[cur][1][0];
#pragma unroll
      for (int m = 0; m < 8; ++m) {
        const int R = wm * 128 + m * 16 + lr;
        af[m] = ldh8(&Ar[R * 32 + ((lg ^ ((R >> 1) & 3)) << 3)]);
      }
      { const int R = wn * 64 + lr;      b0 = ldh8(&Br[R * 32 + ((lg ^ ((R >> 1) & 3)) << 3)]); }
      { const int R = wn * 64 + 16 + lr; b1 = ldh8(&Br[R * 32 + ((lg ^ ((R >> 1) & 3)) << 3)]); }
      stage256x32(Abase + ktn + 32, K, &ldsA[nxt][1][0], w, l);
      __builtin_amdgcn_s_barrier();
      LGKM0_SB;
      __builtin_amdgcn_s_setprio(1);
#pragma unroll
      for (int m = 0; m < 8; ++m) {
        acc[m][0] = __builtin_amdgcn_mfma_f32_16x16x32_f16(af[m], b0, acc[m][0], 0, 0, 0);
        acc[m][1] = __builtin_amdgcn_mfma_f32_16x16x32_f16(af[m], b1, acc[m][1], 0, 0, 0);
      }
      __builtin_amdgcn_s_setprio(0);
      __builtin_amdgcn_sched_barrier(0);
      __builtin_amdgcn_s_barrier();
    }
    // ---------------- phase 3: k-half 1, n-half 1
    {
      const unsigned short* Br = &ldsB[cur][1][0];
      { const int R = wn * 64 + 32 + lr; b0 = ldh8(&Br[R * 32 + ((lg ^ ((R >> 1) & 3)) << 3)]); }
      { const int R = wn * 64 + 48 + lr; b1 = ldh8(&Br[R * 32 + ((lg ^ ((R >> 1) & 3)) << 3)]); }
      stage256x32(Bbase + ktn + 32, K, &ldsB[nxt][1][0], w, l);
      __builtin_amdgcn_s_barrier();
      LGKM0_SB;
      __builtin_amdgcn_s_setprio(1);
#pragma unroll
      for (int m = 0; m < 8; ++m) {
        acc[m][2] = __builtin_amdgcn_mfma_f32_16x16x32_f16(af[m], b0, acc[m][2], 0, 0, 0);
        acc[m][3] = __builtin_amdgcn_mfma_f32_16x16x32_f16(af[m], b1, acc[m][3], 0, 0, 0);
      }
      __builtin_amdgcn_s_setprio(0);
      __builtin_amdgcn_sched_barrier(0);
      asm volatile("s_waitcnt vmcnt(4)" ::: "memory");  // A-k0(t+1),B-k0(t+1) landed
      __builtin_amdgcn_s_barrier();
    }
  }
  asm volatile("s_waitcnt vmcnt(0)" ::: "memory");  // drain dangling prefetch

#pragma unroll
  for (int m = 0; m < 8; ++m) {
#pragma unroll
    for (int n = 0; n < 4; ++n) {
      const int gn = n0 + wn * 64 + n * 16 + lr;
#pragma unroll
      for (int reg = 0; reg < 4; ++reg) {
        const int gm = m0 + wm * 128 + m * 16 + lg * 4 + reg;
        const float v = acc[m][n][reg];
        if constexpr (MODE == 0) {
          const int which = gn >> 11;
          const int head = (gn >> 8) & 7;
          const int d = gn & 255;
          const int b = gm >> 10, t = gm & 1023;
          unsigned short* dst = (which == 0) ? qb : (which == 1) ? kb : vb;
          dst[(((size_t)b * 8 + head) * 1024 + t) * 256 + d] = f2h(v);
        } else {
          outp[(size_t)gm * 2048 + gn] = v + resid[(size_t)gm * 2048 + gn];
        }
      }
    }
  }
}

// ---------------------------------------------------------------- flash attention
// 8 waves x 16 q-rows = 128 q-rows/block; KVBLK=64 (16 iterations).
// All LDS rows are 64 halves (128B) or 256 halves (512B): row*stride % 32banks
// == 0, so the XOR slot-swizzles spread lanes over all 32 banks (round-2
// verified: 0 bank conflicts at this geometry).
// K: double-buffered (global_load_lds, pre-swizzled source).
// V: single-buffered, staged at iter start; counted vmcnt(4) before PV keeps
// the K(t+1) prefetch in flight across the barrier.
__global__ __launch_bounds__(512, 2) void attn_kernel(
    const unsigned short* __restrict__ qbuf, const unsigned short* __restrict__ kbuf,
    const unsigned short* __restrict__ vT, const int* __restrict__ mask,
    const int* __restrict__ pre, unsigned short* __restrict__ ctx) {
  __shared__ __align__(16) unsigned short klds[2][64 * 256];  // 2 x 32 KB
  __shared__ __align__(16) unsigned short vlds[256 * 64];     // 32 KB
  __shared__ __align__(16) unsigned short plds[8 * 16 * 64];  // 16 KB
  __shared__ int mlds[1024];                                  // 4 KB
  const int tid = threadIdx.x;
  const int w = tid >> 6, l = tid & 63;
  const int lr = l & 15, lg = l >> 4;
  // XCD-chunk swizzle: 512 blocks; the 8 q-blocks of each bh share one XCD.
  const int j = blockIdx.x;
  const int swz = (j & 7) * 64 + (j >> 3);
  const int bh = swz >> 3, qb = swz & 7;
  const int b = bh >> 3, h = bh & 7;
  const int isPre = pre[0];
  const int qrow0 = qb * 128 + w * 16;

  const unsigned short* kbh = kbuf + (size_t)bh * 1024 * 256;
  const unsigned short* vbh = vT + (size_t)bh * 256 * 1024;
  unsigned short* pl = plds + w * 1024;

  // mask row -> LDS
  *(int2*)&mlds[tid * 2] = *(const int2*)&mask[b * 1024 + tid * 2];

  // Q fragments (held in registers for all 16 kv steps)
  const unsigned short* qrow =
      qbuf + ((size_t)bh * 1024 + qrow0 + lr) * 256 + lg * 8;
  f16x8 qf[8];
#pragma unroll
  for (int kk = 0; kk < 8; ++kk) qf[kk] = ldh8(qrow + kk * 32);

  // staging lane geometry
  const int krow_in = l >> 5;   // K: row within 2-row chunk
  const int ksp = l & 31;       // K: 16B slot within 512B row
  const int vrow_in = l >> 3;   // V: row within 8-row chunk
  const int vsp = l & 7;        // V: 16B slot within 128B row

  // prologue: stage K(0) -> klds[0]  (4 issues/thread)
#pragma unroll
  for (int ii = 0; ii < 4; ++ii) {
    const int c = w * 4 + ii;
    const int kr = c * 2 + krow_in;
    const unsigned short* ksrc =
        kbh + (size_t)kr * 256 + ((ksp ^ (kr & 7)) << 3);
    GLD_LDS16(ksrc, &klds[0][c * 512]);
  }
  __syncthreads();

  const f32x4 zero = {0.f, 0.f, 0.f, 0.f};
  f32x4 oacc[16];
#pragma unroll
  for (int dt = 0; dt < 16; ++dt) oacc[dt] = zero;
  float mrow[4] = {-1e30f, -1e30f, -1e30f, -1e30f};
  float lrow[4] = {0.f, 0.f, 0.f, 0.f};

  for (int t = 0; t < 16; ++t) {
    const int kv0 = t * 64;
    // ---- stage V(t) (4 issues), then K(t+1) (4 issues, wraps on last iter)
#pragma unroll
    for (int ii = 0; ii < 4; ++ii) {
      const int c = w * 4 + ii;
      const int dr = c * 8 + vrow_in;
      const unsigned short* vsrc =
          vbh + (size_t)dr * 1024 + kv0 + ((vsp ^ ((dr >> 1) & 7)) << 3);
      GLD_LDS16(vsrc, &vlds[c * 512]);
    }
    __builtin_amdgcn_sched_barrier(0);
    {
      const int kvn = ((t + 1) & 15) * 64;
#pragma unroll
      for (int ii = 0; ii < 4; ++ii) {
        const int c = w * 4 + ii;
        const int kr = c * 2 + krow_in;
        const unsigned short* ksrc =
            kbh + (size_t)(kvn + kr) * 256 + ((ksp ^ (kr & 7)) << 3);
        GLD_LDS16(ksrc, &klds[(t + 1) & 1][c * 512]);
      }
    }
    __builtin_amdgcn_sched_barrier(0);

    // ---- QK^T from klds[t&1]: 4 n-tiles x 8 kk = 32 MFMA
    const unsigned short* kcur = klds[t & 1];
    f32x4 sacc[4];
#pragma unroll
    for (int n = 0; n < 4; ++n) sacc[n] = zero;
    __builtin_amdgcn_s_setprio(1);
#pragma unroll
    for (int kk = 0; kk < 8; ++kk) {
#pragma unroll
      for (int n = 0; n < 4; ++n) {
        const int row = n * 16 + lr;
        const f16x8 kf =
            ldh8(&kcur[row * 256 + (((kk * 4 + lg) ^ (row & 7)) << 3)]);
        sacc[n] = __builtin_amdgcn_mfma_f32_16x16x32_f16(qf[kk], kf, sacc[n], 0, 0, 0);
      }
    }
    __builtin_amdgcn_s_setprio(0);

    // ---- mask + online softmax (rows owned by (lg,reg); cols over (n,lr))
    int mv[4];
#pragma unroll
    for (int n = 0; n < 4; ++n) mv[n] = mlds[kv0 + n * 16 + lr];
    float sf[4];
#pragma unroll
    for (int reg = 0; reg < 4; ++reg) {
      const int qg = qrow0 + lg * 4 + reg;
      float mx = -3.0e38f;
#pragma unroll
      for (int n = 0; n < 4; ++n) {
        const int kvg = kv0 + n * 16 + lr;
        float s = sacc[n][reg];
        const bool msk = (mv[n] != 0) || (isPre && (kvg > qg));
        s = msk ? -1e9f : s;
        s *= 0.0625f;  // masked_fill THEN scale, matching reference
        sacc[n][reg] = s;
        mx = fmaxf(mx, s);
      }
      mx = fmaxf(mx, __shfl_xor(mx, 1));
      mx = fmaxf(mx, __shfl_xor(mx, 2));
      mx = fmaxf(mx, __shfl_xor(mx, 4));
      mx = fmaxf(mx, __shfl_xor(mx, 8));
      const float mnew = fmaxf(mrow[reg], mx);
      sf[reg] = __expf(mrow[reg] - mnew);
      float ps = 0.f;
#pragma unroll
      for (int n = 0; n < 4; ++n) {
        const float pv = __expf(sacc[n][reg] - mnew);
        sacc[n][reg] = pv;
        ps += pv;
      }
      ps += __shfl_xor(ps, 1);
      ps += __shfl_xor(ps, 2);
      ps += __shfl_xor(ps, 4);
      ps += __shfl_xor(ps, 8);
      lrow[reg] = lrow[reg] * sf[reg] + ps;
      mrow[reg] = mnew;
    }
#pragma unroll
    for (int dt = 0; dt < 16; ++dt) {
      f32x4 o = oacc[dt];
      o[0] *= sf[0]; o[1] *= sf[1]; o[2] *= sf[2]; o[3] *= sf[3];
      oacc[dt] = o;
    }

    // ---- P -> per-wave LDS (rows 64 halves; 8 slots, slot ^= (row>>1)&7)
#pragma unroll
    for (int n = 0; n < 4; ++n) {
#pragma unroll
      for (int reg = 0; reg < 4; ++reg) {
        const int row = lg * 4 + reg;
        const int col = n * 16 + lr;
        const int slot = col >> 3;
        pl[row * 64 + (((slot ^ ((row >> 1) & 7)) << 3) | (col & 7))] =
            f2h(sacc[n][reg]);
      }
    }
    asm volatile("s_waitcnt lgkmcnt(0)" ::: "memory");
    __builtin_amdgcn_sched_barrier(0);
    // wait the 4 V-issues (oldest); K(t+1)'s 4 stay in flight
    asm volatile("s_waitcnt vmcnt(4)" ::: "memory");
    __builtin_amdgcn_sched_barrier(0);

    // ---- PV: kb2 selects kv-half (0..31 / 32..63); 2 x 16 = 32 MFMA
    __builtin_amdgcn_s_setprio(1);
#pragma unroll
    for (int kb2 = 0; kb2 < 2; ++kb2) {
      const f16x8 pf = ldh8(
          &pl[lr * 64 + (((kb2 * 4 + lg) ^ ((lr >> 1) & 7)) << 3)]);
#pragma unroll
      for (int dt = 0; dt < 16; ++dt) {
        const int row = dt * 16 + lr;
        const f16x8 vf = ldh8(
            &vlds[row * 64 + (((kb2 * 4 + lg) ^ ((row >> 1) & 7)) << 3)]);
        oacc[dt] = __builtin_amdgcn_mfma_f32_16x16x32_f16(pf, vf, oacc[dt], 0, 0, 0);
      }
    }
    __builtin_amdgcn_s_setprio(0);
    __syncthreads();  // drains remaining vmcnt (K prefetch) + lgkm, then barrier
  }

  float inv[4];
#pragma unroll
  for (int reg = 0; reg < 4; ++reg) inv[reg] = 1.0f / lrow[reg];
#pragma unroll
  for (int dt = 0; dt < 16; ++dt) {
#pragma unroll
    for (int reg = 0; reg < 4; ++reg) {
      const int qg = qrow0 + lg * 4 + reg;
      ctx[((size_t)b * 1024 + qg) * 2048 + h * 256 + dt * 16 + lr] =
          f2h(oacc[dt][reg] * inv[reg]);
    }
  }
}

// ---------------------------------------------------------------- launch
extern "C" void kernel_launch(void* const* d_in, const int* in_sizes, int n_in,
                              void* d_out, int out_size, void* d_ws,
                              size_t ws_size, hipStream_t stream) {
  const float* x_in = (const float*)d_in[0];
  const int* mask = (const int*)d_in[1];
  const float* lnw = (const float*)d_in[2];
  const float* lnb = (const float*)d_in[3];
  const float* qkvw = (const float*)d_in[4];
  const float* ow = (const float*)d_in[5];
  const int* ispre = (const int*)d_in[6];
  float* out = (float*)d_out;
  char* ws = (char*)d_ws;

  const size_t SZ = 33554432;  // 8192*2048*2 bytes
  unsigned short* xln = (unsigned short*)(ws);           // dead after gemm_qkv
  unsigned short* wTq = (unsigned short*)(ws + SZ);      // 25165824
  unsigned short* oT = (unsigned short*)(ws + SZ + 25165824);  // 8388608
  unsigned short* qb;
  unsigned short* kb;
  unsigned short* vb;
  const size_t base = SZ + 25165824 + 8388608;  // 67108864
  if (ws_size >= base + 3 * SZ) {
    qb = (unsigned short*)(ws + base);
    kb = (unsigned short*)(ws + base + SZ);
    vb = (unsigned short*)(ws + base + 2 * SZ);
  } else {
    // fallback: park q/k in d_out (dead before the final GEMM writes it)
    qb = (unsigned short*)d_out;
    kb = qb + SZ / 2;
    vb = (unsigned short*)(ws + base);
  }
  unsigned short* vT = xln;  // alias: xln dead once gemm_qkv is done
  unsigned short* ctxb = vb; // alias: vb dead once transpose_v is done

  ln_kernel<<<8192, 256, 0, stream>>>(x_in, lnw, lnb, xln);
  transpose_w_kernel<<<dim3(192, 64), dim3(32, 8), 0, stream>>>(qkvw, wTq, 2048, 6144);
  transpose_w_kernel<<<dim3(64, 64), dim3(32, 8), 0, stream>>>(ow, oT, 2048, 2048);
  gemm256_kernel<0><<<768, 512, 0, stream>>>(
      xln, wTq, 2048, 24, qb, kb, vb, nullptr, nullptr);
  transpose_v_kernel<<<dim3(8, 32, 64), dim3(32, 8), 0, stream>>>(vb, vT);
  attn_kernel<<<512, 512, 0, stream>>>(qb, kb, vT, mask, ispre, ctxb);
  gemm256_kernel<1><<<256, 512, 0, stream>>>(
      ctxb, oT, 2048, 8, nullptr, nullptr, nullptr, x_in, out);
}